// Round 10
// baseline (5100.103 us; speedup 1.0000x reference)
//
#include <hip/hip_runtime.h>

typedef _Float16 h2_t __attribute__((ext_vector_type(2)));

#define HID  100
#define TENC 4096
#define TDEC 4096
#define NCLS 6
#define NSTEP (TENC + TDEC - 1)   // 8191 recurrence steps total
#define NTHR 256                  // 4 waves, one per SIMD

__device__ __forceinline__ float sigm(float v)  { return __builtin_amdgcn_rcpf(1.0f + __expf(-v)); }
__device__ __forceinline__ float tanh_(float v) { return 1.0f - 2.0f * __builtin_amdgcn_rcpf(1.0f + __expf(2.0f * v)); }

// lgkm-only barrier: does NOT drain vmcnt -> gx prefetch + hsto stores stay in flight.
#define SYNC_LDS() asm volatile("s_waitcnt lgkmcnt(0)\n\ts_barrier" ::: "memory")

__device__ __forceinline__ float packh2(float a, float b) {
    h2_t p; p[0] = (_Float16)a; p[1] = (_Float16)b;
    return __builtin_bit_cast(float, p);
}

// Precompute gate-input streams: gxs[st][cell] = (i,f,g,o) of
// Wih @ input_st + bih + bhh, packed 4 x f16 = uint2.
// st < TENC: encoder (input = x[st]); st >= TENC: decoder step st-TENC
// (teacher_forcing_ratio==1 -> input is always the label y[st-TENC]).
__global__ __launch_bounds__(256)
void gx_k(const float* __restrict__ x, const int* __restrict__ y,
          const float* __restrict__ eWih, const float* __restrict__ ebih,
          const float* __restrict__ ebhh, const float* __restrict__ dWih,
          const float* __restrict__ dbih, const float* __restrict__ dbhh,
          uint2* __restrict__ gxs)
{
    const int idx = blockIdx.x * 256 + threadIdx.x;
    if (idx >= NSTEP * HID) return;
    const int st   = idx / HID;
    const int cell = idx - st * HID;
    float g[4];
    if (st < TENC) {
        const float x0 = x[3*st], x1 = x[3*st+1], x2 = x[3*st+2];
        #pragma unroll
        for (int r = 0; r < 4; ++r) {
            const int row = cell + r * HID;
            g[r] = eWih[row*3]*x0 + eWih[row*3+1]*x1 + eWih[row*3+2]*x2
                 + ebih[row] + ebhh[row];
        }
    } else {
        const float yf = (float)y[st - TENC];
        #pragma unroll
        for (int r = 0; r < 4; ++r) {
            const int row = cell + r * HID;
            g[r] = dWih[row]*yf + dbih[row] + dbhh[row];
        }
    }
    uint2 u;
    u.x = __builtin_bit_cast(unsigned, packh2(g[0], g[1]));
    u.y = __builtin_bit_cast(unsigned, packh2(g[2], g[3]));
    gxs[idx] = u;
}

// v7 = R7's exact skeleton (the only shape that allocated ~116 VGPRs and hit
// 1217 cyc/step) + gx stream grafted minimally. R9's regression was the
// STEP_BODY double-instantiation -> live-range splitting -> wf demoted to
// scratch (VGPR_Count 76 vs ~105 demand). Here: SINGLE loop body, p^=1,
// same variable structure as R7.
// 4 waves; lane l: ci=l&31, half=l>>5, cell=w*32+ci (2 lanes/cell).
// Lane holds 4 gate rows x its k-half = 4x25 packed-f16 pairs (100 VGPRs).
// Step: 7 DS reads (h k-half) -> seed accumulators with prefetched gx
// (half1, registers, zero latency; half0 seeds 0) -> 100 fdot2 ->
// 4 shfl_xor(32) k-reduction -> both halves activate (c replicated; half1
// needs hn for hsto) -> half0 writes h f16 to LDS, half1 writes decoder h
// history to global (unfenced) -> ONE lgkm-only barrier.
__global__ __launch_bounds__(NTHR, 1)
void lstm_rec(const float* __restrict__ eWhh,   // [400*HID]
              const float* __restrict__ dWhh,   // [400*HID]
              const uint2* __restrict__ gxs,    // [NSTEP+1][HID] (last row = pad)
              float* __restrict__ hsto)         // [(TDEC-1)*HID]
{
    __shared__ __align__(16) _Float16 hbuf[2][2][64];  // [parity][k-half][50 used]

    const int  t    = threadIdx.x;
    const int  w    = t >> 6;
    const int  l    = t & 63;
    const int  ci   = l & 31;
    const int  half = l >> 5;
    const int  cell = w * 32 + ci;
    const bool live = (cell < HID);
    const bool gldr = live && (half == 1);   // gx loader / hsto writer lanes
    const int  k0   = half * 50;

    float wf[4][25];
    float c = 0.0f;

    if (t < 256) ((_Float16*)hbuf)[t] = (_Float16)0.0f;

    #pragma unroll
    for (int r = 0; r < 4; ++r)
        #pragma unroll
        for (int j = 0; j < 25; ++j) wf[r][j] = 0.0f;
    if (live) {
        #pragma unroll
        for (int r = 0; r < 4; ++r) {
            const int row = cell + r * HID;
            #pragma unroll
            for (int j = 0; j < 25; ++j)
                wf[r][j] = packh2(eWhh[row*HID + k0 + 2*j], eWhh[row*HID + k0 + 2*j + 1]);
        }
    }
    #pragma unroll
    for (int r = 0; r < 4; ++r)
        #pragma unroll
        for (int j = 0; j < 25; ++j)
            asm volatile("" : "+v"(wf[r][j]));   // block remat-sinking into the loop
    __syncthreads();

    uint2 gcur = gldr ? gxs[cell] : make_uint2(0u, 0u);   // gx for step 0
    int p = 0;

    // ================ encoder: 4096 steps ================
    for (int s = 0; s < TENC; ++s) {
        const float4* h4 = (const float4*)&hbuf[p][half][0];
        float hp[25];
        #pragma unroll
        for (int j = 0; j < 6; ++j) {
            const float4 v = h4[j];
            hp[4*j+0] = v.x; hp[4*j+1] = v.y; hp[4*j+2] = v.z; hp[4*j+3] = v.w;
        }
        hp[24] = ((const float*)h4)[24];

        // seed with prefetched gx (registers -> zero latency on the chain head)
        float a0, a1, a2, a3;
        if (half == 1) {
            const h2_t g01 = __builtin_bit_cast(h2_t, gcur.x);
            const h2_t g23 = __builtin_bit_cast(h2_t, gcur.y);
            a0 = (float)g01[0]; a1 = (float)g01[1];
            a2 = (float)g23[0]; a3 = (float)g23[1];
        } else { a0 = a1 = a2 = a3 = 0.0f; }

        uint2 gnew = gldr ? gxs[(s + 1) * HID + cell] : make_uint2(0u, 0u);  // prefetch next

        #pragma unroll
        for (int j = 0; j < 25; ++j) {
            const h2_t hh = __builtin_bit_cast(h2_t, hp[j]);
            a0 = __builtin_amdgcn_fdot2(__builtin_bit_cast(h2_t, wf[0][j]), hh, a0, false);
            a1 = __builtin_amdgcn_fdot2(__builtin_bit_cast(h2_t, wf[1][j]), hh, a1, false);
            a2 = __builtin_amdgcn_fdot2(__builtin_bit_cast(h2_t, wf[2][j]), hh, a2, false);
            a3 = __builtin_amdgcn_fdot2(__builtin_bit_cast(h2_t, wf[3][j]), hh, a3, false);
        }
        gcur = gnew;

        a0 += __shfl_xor(a0, 32);          // k-reduction: halves are 32 lanes apart
        a1 += __shfl_xor(a1, 32);
        a2 += __shfl_xor(a2, 32);
        a3 += __shfl_xor(a3, 32);

        const float fi = sigm(a0), ff = sigm(a1), fg = tanh_(a2), fo = sigm(a3);
        c = ff * c + fi * fg;              // replicated in the cell's two lanes
        const float hn = fo * tanh_(c);
        if (half == 0 && live) {
            const int hh2 = (cell < 50) ? 0 : 1;
            hbuf[p ^ 1][hh2][cell - 50*hh2] = (_Float16)hn;
        }
        SYNC_LDS();
        p ^= 1;
    }
    // gcur now holds gxs[TENC] = decoder step 0; h_enc is in hbuf[0].

    // ================ swap to decoder weights (local, no barrier needed) ================
    if (live) {
        #pragma unroll
        for (int r = 0; r < 4; ++r) {
            const int row = cell + r * HID;
            #pragma unroll
            for (int j = 0; j < 25; ++j)
                wf[r][j] = packh2(dWhh[row*HID + k0 + 2*j], dWhh[row*HID + k0 + 2*j + 1]);
        }
    }
    #pragma unroll
    for (int r = 0; r < 4; ++r)
        #pragma unroll
        for (int j = 0; j < 25; ++j)
            asm volatile("" : "+v"(wf[r][j]));

    // ================ decoder: 4095 steps (ratio==1 -> teacher-forced) ================
    for (int s = 0; s < TDEC - 1; ++s) {
        const float4* h4 = (const float4*)&hbuf[p][half][0];
        float hp[25];
        #pragma unroll
        for (int j = 0; j < 6; ++j) {
            const float4 v = h4[j];
            hp[4*j+0] = v.x; hp[4*j+1] = v.y; hp[4*j+2] = v.z; hp[4*j+3] = v.w;
        }
        hp[24] = ((const float*)h4)[24];

        float a0, a1, a2, a3;
        if (half == 1) {
            const h2_t g01 = __builtin_bit_cast(h2_t, gcur.x);
            const h2_t g23 = __builtin_bit_cast(h2_t, gcur.y);
            a0 = (float)g01[0]; a1 = (float)g01[1];
            a2 = (float)g23[0]; a3 = (float)g23[1];
        } else { a0 = a1 = a2 = a3 = 0.0f; }

        uint2 gnew = gldr ? gxs[(TENC + s + 1) * HID + cell] : make_uint2(0u, 0u);

        #pragma unroll
        for (int j = 0; j < 25; ++j) {
            const h2_t hh = __builtin_bit_cast(h2_t, hp[j]);
            a0 = __builtin_amdgcn_fdot2(__builtin_bit_cast(h2_t, wf[0][j]), hh, a0, false);
            a1 = __builtin_amdgcn_fdot2(__builtin_bit_cast(h2_t, wf[1][j]), hh, a1, false);
            a2 = __builtin_amdgcn_fdot2(__builtin_bit_cast(h2_t, wf[2][j]), hh, a2, false);
            a3 = __builtin_amdgcn_fdot2(__builtin_bit_cast(h2_t, wf[3][j]), hh, a3, false);
        }
        gcur = gnew;

        a0 += __shfl_xor(a0, 32);
        a1 += __shfl_xor(a1, 32);
        a2 += __shfl_xor(a2, 32);
        a3 += __shfl_xor(a3, 32);

        const float fi = sigm(a0), ff = sigm(a1), fg = tanh_(a2), fo = sigm(a3);
        c = ff * c + fi * fg;
        const float hn = fo * tanh_(c);
        if (live) {
            if (half == 0) {
                const int hh2 = (cell < 50) ? 0 : 1;
                hbuf[p ^ 1][hh2][cell - 50*hh2] = (_Float16)hn;
            } else {
                hsto[s * HID + cell] = hn;     // global history, never fenced in-loop
            }
        }
        SYNC_LDS();
        p ^= 1;
    }
}

// Parallel logits: out[t][r] = linW[r] . h_t + linb[r], last row zeroed.
__global__ __launch_bounds__(256)
void logits_k(const float* __restrict__ hsto, const float* __restrict__ linW,
              const float* __restrict__ linb, float* __restrict__ out)
{
    const int idx = blockIdx.x * 256 + threadIdx.x;
    if (idx >= TDEC * NCLS) return;
    const int tt = idx / NCLS;
    const int r  = idx % NCLS;
    if (tt >= TDEC - 1) { out[idx] = 0.0f; return; }
    const float* h  = hsto + tt * HID;
    const float* wr = linW + r * HID;
    float a = linb[r];
    #pragma unroll 4
    for (int k = 0; k < HID; ++k) a += wr[k] * h[k];
    out[idx] = a;
}

extern "C" void kernel_launch(void* const* d_in, const int* in_sizes, int n_in,
                              void* d_out, int out_size, void* d_ws, size_t ws_size,
                              hipStream_t stream)
{
    const float* x    = (const float*)d_in[0];
    const int*   y    = (const int*)  d_in[1];
    const float* eWih = (const float*)d_in[2];
    const float* eWhh = (const float*)d_in[3];
    const float* ebih = (const float*)d_in[4];
    const float* ebhh = (const float*)d_in[5];
    const float* dWih = (const float*)d_in[6];
    const float* dWhh = (const float*)d_in[7];
    const float* dbih = (const float*)d_in[8];
    const float* dbhh = (const float*)d_in[9];
    const float* linW = (const float*)d_in[10];
    const float* linb = (const float*)d_in[11];
    float* out  = (float*)d_out;

    float* hsto = (float*)d_ws;                                   // 1.64 MB
    uint2* gxs  = (uint2*)((char*)d_ws + (2u << 20));             // (NSTEP+1)*HID*8 = 6.55 MB

    const int ngx = NSTEP * HID;
    gx_k<<<dim3((ngx + 255) / 256), dim3(256), 0, stream>>>(
        x, y, eWih, ebih, ebhh, dWih, dbih, dbhh, gxs);

    lstm_rec<<<dim3(1), dim3(NTHR), 0, stream>>>(eWhh, dWhh, gxs, hsto);

    const int nout = TDEC * NCLS;
    logits_k<<<dim3((nout + 255) / 256), dim3(256), 0, stream>>>(hsto, linW, linb, out);
}

// Round 11
// 4227.322 us; speedup vs baseline: 1.2065x; 1.2065x over previous
//
#include <hip/hip_runtime.h>

typedef _Float16 h2_t __attribute__((ext_vector_type(2)));

#define HID  100
#define TENC 4096
#define TDEC 4096
#define NCLS 6
#define NSTEP (TENC + TDEC - 1)   // 8191 recurrence steps
#define NTHR 320                  // 4 compute waves + 1 DMA wave

__device__ __forceinline__ float sigm(float v)  { return __builtin_amdgcn_rcpf(1.0f + __expf(-v)); }
__device__ __forceinline__ float tanh_(float v) { return 1.0f - 2.0f * __builtin_amdgcn_rcpf(1.0f + __expf(2.0f * v)); }

// lgkm-only barrier for compute waves: does NOT drain vmcnt -> hsto stores stay in flight.
#define SYNC_LDS() asm volatile("s_waitcnt lgkmcnt(0)\n\ts_barrier" ::: "memory")

typedef __attribute__((address_space(1))) const void gbl_v;
typedef __attribute__((address_space(3))) void       lds_v;

__device__ __forceinline__ float packh2(float a, float b) {
    h2_t p; p[0] = (_Float16)a; p[1] = (_Float16)b;
    return __builtin_bit_cast(float, p);
}

// Precompute gate-input streams: gxs[st][cell] = (i,f,g,o) of
// Wih @ input_st + bih + bhh, packed 4 x f16 = uint2 (8 B).
// st < TENC: encoder (input = x[st]); else decoder step st-TENC
// (teacher_forcing_ratio==1 -> input is always label y[st-TENC]).
__global__ __launch_bounds__(256)
void gx_k(const float* __restrict__ x, const int* __restrict__ y,
          const float* __restrict__ eWih, const float* __restrict__ ebih,
          const float* __restrict__ ebhh, const float* __restrict__ dWih,
          const float* __restrict__ dbih, const float* __restrict__ dbhh,
          uint2* __restrict__ gxs)
{
    const int idx = blockIdx.x * 256 + threadIdx.x;
    if (idx >= NSTEP * HID) return;
    const int st   = idx / HID;
    const int cell = idx - st * HID;
    float g[4];
    if (st < TENC) {
        const float x0 = x[3*st], x1 = x[3*st+1], x2 = x[3*st+2];
        #pragma unroll
        for (int r = 0; r < 4; ++r) {
            const int row = cell + r * HID;
            g[r] = eWih[row*3]*x0 + eWih[row*3+1]*x1 + eWih[row*3+2]*x2
                 + ebih[row] + ebhh[row];
        }
    } else {
        const float yf = (float)y[st - TENC];
        #pragma unroll
        for (int r = 0; r < 4; ++r) {
            const int row = cell + r * HID;
            g[r] = dWih[row]*yf + dbih[row] + dbhh[row];
        }
    }
    uint2 u;
    u.x = __builtin_bit_cast(unsigned, packh2(g[0], g[1]));
    u.y = __builtin_bit_cast(unsigned, packh2(g[2], g[3]));
    gxs[idx] = u;
}

// v8 = R7's exact skeleton (only proven-resident shape: VGPR 116, 1217
// cyc/step) + gx delivered by a DMA WAVE via global_load_lds.
// R9/R10 evidence: ANY in-loop VMEM load result (gx prefetch) makes the
// allocator demote the 100-reg weight array (VGPR 76/72 vs R7's 116).
// global_load_lds has NO result register -> compute waves' loop stays
// VMEM-load-free (hsto store is proven harmless in R7).
// Wave 4 (DMA): per step, lanes 0..49 issue ONE global_load_lds size=16
// (dest = uniform base + lane*16 -> 800 B gx row) into an 8-slot LDS ring,
// 4 steps ahead; s_waitcnt vmcnt(3) guarantees next step's slot is ready;
// s_barrier paired 1:1 with compute waves' SYNC_LDS (8191 each).
// Compute waves 0..3: R7 layout. Lane: ci=l&31, half=l>>5, cell=w*32+ci.
// Lane holds 4 gate rows x its k-half = 4x25 packed-f16 pairs (100 VGPRs).
// Step: 7 DS reads (h k-half) + half1 reads its cell's gx from the ring
// (ds_read_b64) -> seed -> 100 fdot2 -> 4 shfl_xor(32) -> activate (c
// replicated) -> half0 writes h f16, half1 writes hsto (unfenced) -> SYNC.
__global__ __launch_bounds__(NTHR, 1)
void lstm_rec(const float* __restrict__ eWhh,   // [400*HID]
              const float* __restrict__ dWhh,   // [400*HID]
              const uint2* __restrict__ gxs,    // [NSTEP+8][HID]
              float* __restrict__ hsto)         // [(TDEC-1)*HID]
{
    __shared__ __align__(16) _Float16 hbuf[2][2][64];   // [parity][k-half][50 used]
    __shared__ __align__(16) uint2    gxring[8][HID];   // 8 x 800 B gx ring

    const int  t    = threadIdx.x;
    const int  w    = t >> 6;
    const int  l    = t & 63;
    const int  ci   = l & 31;
    const int  half = l >> 5;
    const int  cell = w * 32 + ci;                 // w==4 -> cell>=128 -> live=false
    const bool live = (cell < HID);
    const bool gldr = live && (half == 1);         // gx consumer / hsto writer lanes
    const int  k0   = half * 50;

    float wf[4][25];
    float c = 0.0f;

    if (t < 256) ((_Float16*)hbuf)[t] = (_Float16)0.0f;

    #pragma unroll
    for (int r = 0; r < 4; ++r)
        #pragma unroll
        for (int j = 0; j < 25; ++j) wf[r][j] = 0.0f;
    if (live) {
        #pragma unroll
        for (int r = 0; r < 4; ++r) {
            const int row = cell + r * HID;
            #pragma unroll
            for (int j = 0; j < 25; ++j)
                wf[r][j] = packh2(eWhh[row*HID + k0 + 2*j], eWhh[row*HID + k0 + 2*j + 1]);
        }
    }

    // ---- DMA prelude: fill ring slots 0..3 (drained by the __syncthreads) ----
    if (w == 4) {
        #pragma unroll
        for (int st = 0; st < 4; ++st)
            if (l < 50)
                __builtin_amdgcn_global_load_lds((gbl_v*)&gxs[st * HID + 2 * l],
                                                 (lds_v*)&gxring[st][0], 16, 0, 0);
    }
    __syncthreads();

    // ================ DMA wave: 8191 paired barriers ================
    if (w == 4) {
        for (int s = 0; s < NSTEP; ++s) {
            if (l < 50)
                __builtin_amdgcn_global_load_lds((gbl_v*)&gxs[(s + 4) * HID + 2 * l],
                                                 (lds_v*)&gxring[(s + 4) & 7][0], 16, 0, 0);
            asm volatile("s_waitcnt vmcnt(3)\n\ts_barrier" ::: "memory");
        }
        return;
    }

    int p = 0;

    // ================ encoder: 4096 steps ================
    for (int s = 0; s < TENC; ++s) {
        const float4* h4 = (const float4*)&hbuf[p][half][0];
        float hp[25];
        #pragma unroll
        for (int j = 0; j < 6; ++j) {
            const float4 v = h4[j];
            hp[4*j+0] = v.x; hp[4*j+1] = v.y; hp[4*j+2] = v.z; hp[4*j+3] = v.w;
        }
        hp[24] = ((const float*)h4)[24];

        // seed from ring gx (LDS, no VMEM): half1 lanes only
        float a0, a1, a2, a3;
        if (half == 1) {
            const uint2 gxv = *(const uint2*)&gxring[s & 7][cell];
            const h2_t g01 = __builtin_bit_cast(h2_t, gxv.x);
            const h2_t g23 = __builtin_bit_cast(h2_t, gxv.y);
            a0 = (float)g01[0]; a1 = (float)g01[1];
            a2 = (float)g23[0]; a3 = (float)g23[1];
        } else { a0 = a1 = a2 = a3 = 0.0f; }

        #pragma unroll
        for (int j = 0; j < 25; ++j) {
            const h2_t hh = __builtin_bit_cast(h2_t, hp[j]);
            a0 = __builtin_amdgcn_fdot2(__builtin_bit_cast(h2_t, wf[0][j]), hh, a0, false);
            a1 = __builtin_amdgcn_fdot2(__builtin_bit_cast(h2_t, wf[1][j]), hh, a1, false);
            a2 = __builtin_amdgcn_fdot2(__builtin_bit_cast(h2_t, wf[2][j]), hh, a2, false);
            a3 = __builtin_amdgcn_fdot2(__builtin_bit_cast(h2_t, wf[3][j]), hh, a3, false);
        }

        a0 += __shfl_xor(a0, 32);          // k-reduction: halves 32 lanes apart
        a1 += __shfl_xor(a1, 32);
        a2 += __shfl_xor(a2, 32);
        a3 += __shfl_xor(a3, 32);

        const float fi = sigm(a0), ff = sigm(a1), fg = tanh_(a2), fo = sigm(a3);
        c = ff * c + fi * fg;              // replicated in the cell's two lanes
        const float hn = fo * tanh_(c);
        if (half == 0 && live) {
            const int hh2 = (cell < 50) ? 0 : 1;
            hbuf[p ^ 1][hh2][cell - 50*hh2] = (_Float16)hn;
        }
        SYNC_LDS();
        p ^= 1;
    }

    // ================ swap to decoder weights (no barrier; DMA waits at its own) ================
    if (live) {
        #pragma unroll
        for (int r = 0; r < 4; ++r) {
            const int row = cell + r * HID;
            #pragma unroll
            for (int j = 0; j < 25; ++j)
                wf[r][j] = packh2(dWhh[row*HID + k0 + 2*j], dWhh[row*HID + k0 + 2*j + 1]);
        }
    }

    // ================ decoder: 4095 steps (ratio==1 -> teacher-forced) ================
    for (int s = 0; s < TDEC - 1; ++s) {
        const float4* h4 = (const float4*)&hbuf[p][half][0];
        float hp[25];
        #pragma unroll
        for (int j = 0; j < 6; ++j) {
            const float4 v = h4[j];
            hp[4*j+0] = v.x; hp[4*j+1] = v.y; hp[4*j+2] = v.z; hp[4*j+3] = v.w;
        }
        hp[24] = ((const float*)h4)[24];

        float a0, a1, a2, a3;
        if (half == 1) {
            // global step TENC+s; TENC%8==0 -> slot = s&7
            const uint2 gxv = *(const uint2*)&gxring[s & 7][cell];
            const h2_t g01 = __builtin_bit_cast(h2_t, gxv.x);
            const h2_t g23 = __builtin_bit_cast(h2_t, gxv.y);
            a0 = (float)g01[0]; a1 = (float)g01[1];
            a2 = (float)g23[0]; a3 = (float)g23[1];
        } else { a0 = a1 = a2 = a3 = 0.0f; }

        #pragma unroll
        for (int j = 0; j < 25; ++j) {
            const h2_t hh = __builtin_bit_cast(h2_t, hp[j]);
            a0 = __builtin_amdgcn_fdot2(__builtin_bit_cast(h2_t, wf[0][j]), hh, a0, false);
            a1 = __builtin_amdgcn_fdot2(__builtin_bit_cast(h2_t, wf[1][j]), hh, a1, false);
            a2 = __builtin_amdgcn_fdot2(__builtin_bit_cast(h2_t, wf[2][j]), hh, a2, false);
            a3 = __builtin_amdgcn_fdot2(__builtin_bit_cast(h2_t, wf[3][j]), hh, a3, false);
        }

        a0 += __shfl_xor(a0, 32);
        a1 += __shfl_xor(a1, 32);
        a2 += __shfl_xor(a2, 32);
        a3 += __shfl_xor(a3, 32);

        const float fi = sigm(a0), ff = sigm(a1), fg = tanh_(a2), fo = sigm(a3);
        c = ff * c + fi * fg;
        const float hn = fo * tanh_(c);
        if (live) {
            if (half == 0) {
                const int hh2 = (cell < 50) ? 0 : 1;
                hbuf[p ^ 1][hh2][cell - 50*hh2] = (_Float16)hn;
            } else {
                hsto[s * HID + cell] = hn;     // global history, never fenced in-loop
            }
        }
        SYNC_LDS();
        p ^= 1;
    }
}

// Parallel logits: out[t][r] = linW[r] . h_t + linb[r], last row zeroed.
__global__ __launch_bounds__(256)
void logits_k(const float* __restrict__ hsto, const float* __restrict__ linW,
              const float* __restrict__ linb, float* __restrict__ out)
{
    const int idx = blockIdx.x * 256 + threadIdx.x;
    if (idx >= TDEC * NCLS) return;
    const int tt = idx / NCLS;
    const int r  = idx % NCLS;
    if (tt >= TDEC - 1) { out[idx] = 0.0f; return; }
    const float* h  = hsto + tt * HID;
    const float* wr = linW + r * HID;
    float a = linb[r];
    #pragma unroll 4
    for (int k = 0; k < HID; ++k) a += wr[k] * h[k];
    out[idx] = a;
}

extern "C" void kernel_launch(void* const* d_in, const int* in_sizes, int n_in,
                              void* d_out, int out_size, void* d_ws, size_t ws_size,
                              hipStream_t stream)
{
    const float* x    = (const float*)d_in[0];
    const int*   y    = (const int*)  d_in[1];
    const float* eWih = (const float*)d_in[2];
    const float* eWhh = (const float*)d_in[3];
    const float* ebih = (const float*)d_in[4];
    const float* ebhh = (const float*)d_in[5];
    const float* dWih = (const float*)d_in[6];
    const float* dWhh = (const float*)d_in[7];
    const float* dbih = (const float*)d_in[8];
    const float* dbhh = (const float*)d_in[9];
    const float* linW = (const float*)d_in[10];
    const float* linb = (const float*)d_in[11];
    float* out  = (float*)d_out;

    float* hsto = (float*)d_ws;                                   // 1.64 MB
    uint2* gxs  = (uint2*)((char*)d_ws + (2u << 20));             // (NSTEP+8)*HID*8 = 6.56 MB

    const int ngx = NSTEP * HID;
    gx_k<<<dim3((ngx + 255) / 256), dim3(256), 0, stream>>>(
        x, y, eWih, ebih, ebhh, dWih, dbih, dbhh, gxs);

    lstm_rec<<<dim3(1), dim3(NTHR), 0, stream>>>(eWhh, dWhh, gxs, hsto);

    const int nout = TDEC * NCLS;
    logits_k<<<dim3((nout + 255) / 256), dim3(256), 0, stream>>>(hsto, linW, linb, out);
}